// Round 2
// baseline (1958.083 us; speedup 1.0000x reference)
//
#include <hip/hip_runtime.h>

// ---- problem constants (fixed by reference) ----
#define T_TOK 8192      // B*S tokens
#define DDIM  1024
#define HDIM  4096
#define NEXP  8
#define TOPK  2

#define NSLOT_CAP 20480          // 16384 + 8*127 pad, rounded up
#define CHUNK     4096           // slots per hidden chunk
#define NCHUNK    5

typedef __attribute__((ext_vector_type(8))) short short8;  // 8 bf16 = 4 VGPRs
typedef __attribute__((ext_vector_type(4))) float f32x4;
typedef unsigned short u16;

// ---- workspace layout (bytes); total ~454 MB ----
#define OFF_RIDX  0x0ul          // [T][2] int
#define OFF_RW    0x10000ul      // [T][2] float
#define OFF_SPOS  0x20000ul      // [T][2] int (slot position per (t,k))
#define OFF_OFFS  0x30000ul      // [9] int
#define OFF_CURS  0x30100ul      // [8] int
#define OFF_TILEE 0x30200ul      // [NSLOT_CAP/128] int
#define OFF_STOK  0x31000ul      // [NSLOT_CAP] int
#define OFF_SWT   0x45000ul      // [NSLOT_CAP] float
#define OFF_ZBF   0x59000ul      // 2048 bf16 zeros (pad-row source)
#define OFF_XHI   0x100000ul     // [T][D] bf16 hi
#define OFF_XLO   0x1100000ul    // [T][D] bf16 lo
#define OFF_W1H   0x2100000ul    // [E][H][D] bf16 hi (transposed!)
#define OFF_W1L   0x6100000ul
#define OFF_W2H   0xA100000ul    // [E][D][H] bf16 hi (transposed!)
#define OFF_W2L   0xE100000ul
#define OFF_HIDH  0x12100000ul   // [CHUNK][H] bf16 hi
#define OFF_HIDL  0x14100000ul
#define OFF_OSLOT 0x16100000ul   // [NSLOT_CAP][D] fp32 per-slot output

__device__ __forceinline__ u16 f2bf(float f) {          // RNE fp32->bf16
    unsigned u = __float_as_uint(f);
    u += 0x7fffu + ((u >> 16) & 1u);
    return (u16)(u >> 16);
}
__device__ __forceinline__ float bf2f(u16 h) {
    return __uint_as_float(((unsigned)h) << 16);
}
__device__ __forceinline__ float gelu_f(float v) {
    // jax.nn.gelu approximate=True
    float u  = 0.7978845608028654f * v * (1.0f + 0.044715f * v * v);
    float ex = __expf(2.0f * u);
    float th = 1.0f - 2.0f / (ex + 1.0f);
    return 0.5f * v * (1.0f + th);
}
__device__ __forceinline__ void gload16(const void* g, void* l) {
    // async global->LDS, 16B/lane; LDS dest = wave-uniform base + lane*16
    __builtin_amdgcn_global_load_lds((const __attribute__((address_space(1))) unsigned*)g,
                                     (__attribute__((address_space(3))) unsigned*)l, 16, 0, 0);
}

// ---------------- router: one wave per token (fp32 exact) ----------------
__global__ void k_router(const float* __restrict__ x, const float* __restrict__ Wr,
                         int* __restrict__ ridx, float* __restrict__ rw) {
    int gt   = (blockIdx.x * blockDim.x + threadIdx.x) >> 6;
    int lane = threadIdx.x & 63;
    if (gt >= T_TOK) return;
    const float* xr = x + (size_t)gt * DDIM;
    float acc[NEXP];
#pragma unroll
    for (int e = 0; e < NEXP; ++e) acc[e] = 0.f;
#pragma unroll
    for (int j = 0; j < DDIM / 64; ++j) {
        float xv = xr[j * 64 + lane];
        const float4 w0 = *(const float4*)(Wr + (size_t)(j * 64 + lane) * NEXP);
        const float4 w1 = *(const float4*)(Wr + (size_t)(j * 64 + lane) * NEXP + 4);
        acc[0] += xv * w0.x; acc[1] += xv * w0.y; acc[2] += xv * w0.z; acc[3] += xv * w0.w;
        acc[4] += xv * w1.x; acc[5] += xv * w1.y; acc[6] += xv * w1.z; acc[7] += xv * w1.w;
    }
#pragma unroll
    for (int off = 32; off > 0; off >>= 1) {
#pragma unroll
        for (int e = 0; e < NEXP; ++e) acc[e] += __shfl_xor(acc[e], off, 64);
    }
    if (lane == 0) {
        float mx = acc[0];
#pragma unroll
        for (int e = 1; e < NEXP; ++e) mx = fmaxf(mx, acc[e]);
        float p[NEXP]; float s = 0.f;
#pragma unroll
        for (int e = 0; e < NEXP; ++e) { p[e] = __expf(acc[e] - mx); s += p[e]; }
        float inv = 1.f / s;
        int i0 = 0;
#pragma unroll
        for (int e = 1; e < NEXP; ++e) if (acc[e] > acc[i0]) i0 = e;   // ties -> lowest idx
        int i1 = (i0 == 0) ? 1 : 0;
#pragma unroll
        for (int e = 0; e < NEXP; ++e) if (e != i0 && acc[e] > acc[i1]) i1 = e;
        float w0 = 0.f, w1 = 0.f;
#pragma unroll
        for (int e = 0; e < NEXP; ++e) { if (e == i0) w0 = p[e]; if (e == i1) w1 = p[e]; }
        ridx[gt * 2 + 0] = i0; ridx[gt * 2 + 1] = i1;
        rw  [gt * 2 + 0] = w0 * inv; rw[gt * 2 + 1] = w1 * inv;
    }
}

// ---------------- counts -> padded offsets -> pad slots (+ zero zbf) ----------------
__global__ void k_offsets(const int* __restrict__ ridx, int* __restrict__ offs,
                          int* __restrict__ curs, int* __restrict__ tilee,
                          int* __restrict__ stok, float* __restrict__ swt,
                          u16* __restrict__ zbf) {
    __shared__ int scnt[NEXP];
    __shared__ int soff[NEXP + 1];
    int tid = threadIdx.x;
    for (int i = tid; i < 2048; i += 256) zbf[i] = 0;   // ws is poisoned each call
    if (tid < NEXP) scnt[tid] = 0;
    __syncthreads();
    int c[NEXP];
#pragma unroll
    for (int q = 0; q < NEXP; ++q) c[q] = 0;
    for (int i = tid; i < T_TOK * TOPK; i += 256) {
        int e = ridx[i];
#pragma unroll
        for (int q = 0; q < NEXP; ++q) c[q] += (e == q) ? 1 : 0;
    }
#pragma unroll
    for (int off = 32; off > 0; off >>= 1) {
#pragma unroll
        for (int q = 0; q < NEXP; ++q) c[q] += __shfl_xor(c[q], off, 64);
    }
    if ((tid & 63) == 0) {
#pragma unroll
        for (int q = 0; q < NEXP; ++q) atomicAdd(&scnt[q], c[q]);
    }
    __syncthreads();
    if (tid == 0) {
        int o = 0;
        for (int q = 0; q < NEXP; ++q) {
            soff[q] = o;
            o += (scnt[q] + 127) & ~127;
        }
        soff[NEXP] = o;
        for (int q = 0; q <= NEXP; ++q) offs[q] = soff[q];
        for (int q = 0; q < NEXP; ++q) curs[q] = soff[q];
        for (int tt = 0; tt < NSLOT_CAP / 128; ++tt) {
            int e = -1;
            for (int q = 0; q < NEXP; ++q)
                if (tt * 128 >= soff[q] && tt * 128 < soff[q + 1]) e = q;
            tilee[tt] = e;
        }
    }
    __syncthreads();
    int total = soff[NEXP];
    for (int sIdx = tid; sIdx < NSLOT_CAP; sIdx += 256) {
        bool pad = (sIdx >= total);
        if (!pad) {
            int e = 0;
#pragma unroll
            for (int q = 1; q < NEXP; ++q) if (sIdx >= soff[q]) e = q;
            if (sIdx >= soff[e] + scnt[e]) pad = true;
        }
        if (pad) { stok[sIdx] = -1; swt[sIdx] = 0.f; }
    }
}

// ---------------- scatter tokens into slots (wave-aggregated atomics) ----------------
__global__ void k_scatter(const int* __restrict__ ridx, const float* __restrict__ rw,
                          int* __restrict__ curs, int* __restrict__ stok,
                          float* __restrict__ swt, int* __restrict__ spos) {
    int t    = blockIdx.x * 256 + threadIdx.x;
    int lane = threadIdx.x & 63;
#pragma unroll
    for (int k = 0; k < TOPK; ++k) {
        int e   = ridx[t * 2 + k];
        float w = rw[t * 2 + k];
#pragma unroll
        for (int q = 0; q < NEXP; ++q) {
            unsigned long long m = __ballot(e == q);
            if (e == q) {
                int rank   = __popcll(m & ((1ull << lane) - 1ull));
                int leader = __ffsll((unsigned long long)m) - 1;
                int base = 0;
                if (lane == leader) base = atomicAdd(&curs[q], __popcll(m));
                base = __shfl(base, leader, 64);
                int pos = base + rank;
                stok[pos] = t;
                swt[pos]  = w;
                spos[t * 2 + k] = pos;
            }
        }
    }
}

// ---------------- fp32 -> (hi,lo) bf16, elementwise (for x) ----------------
__global__ void k_split_x(const float* __restrict__ x, u16* __restrict__ hi,
                          u16* __restrict__ lo) {
    for (int i = blockIdx.x * 256 + threadIdx.x; i < T_TOK * DDIM / 4; i += gridDim.x * 256) {
        float4 v = ((const float4*)x)[i];
        u16 h0 = f2bf(v.x), h1 = f2bf(v.y), h2 = f2bf(v.z), h3 = f2bf(v.w);
        ushort4 hv; hv.x = h0; hv.y = h1; hv.z = h2; hv.w = h3;
        ushort4 lv;
        lv.x = f2bf(v.x - bf2f(h0)); lv.y = f2bf(v.y - bf2f(h1));
        lv.z = f2bf(v.z - bf2f(h2)); lv.w = f2bf(v.w - bf2f(h3));
        ((ushort4*)hi)[i] = hv;
        ((ushort4*)lo)[i] = lv;
    }
}

// ---------------- fp32 [E][R][C] -> transposed (hi,lo) bf16 [E][C][R] ----------------
__global__ __launch_bounds__(256) void k_split_w(const float* __restrict__ Wsrc,
        u16* __restrict__ hi, u16* __restrict__ lo, int R, int C) {
    __shared__ float t[32][33];
    const int e  = blockIdx.z;
    const int r0 = blockIdx.x * 32, c0 = blockIdx.y * 32;
    const float* src = Wsrc + (size_t)e * R * C;
    const int rr = threadIdx.x >> 3, cc = (threadIdx.x & 7) * 4;
    float4 v = *(const float4*)(src + (size_t)(r0 + rr) * C + c0 + cc);
    t[rr][cc] = v.x; t[rr][cc + 1] = v.y; t[rr][cc + 2] = v.z; t[rr][cc + 3] = v.w;
    __syncthreads();
    const int orow = threadIdx.x >> 3, oc = (threadIdx.x & 7) * 4;
    ushort4 hv, lv;
    float f0 = t[oc + 0][orow], f1 = t[oc + 1][orow], f2 = t[oc + 2][orow], f3 = t[oc + 3][orow];
    hv.x = f2bf(f0); hv.y = f2bf(f1); hv.z = f2bf(f2); hv.w = f2bf(f3);
    lv.x = f2bf(f0 - bf2f(hv.x)); lv.y = f2bf(f1 - bf2f(hv.y));
    lv.z = f2bf(f2 - bf2f(hv.z)); lv.w = f2bf(f3 - bf2f(hv.w));
    size_t ob = ((size_t)e * C + c0 + orow) * R + r0 + oc;
    *(ushort4*)(hi + ob) = hv;
    *(ushort4*)(lo + ob) = lv;
}

// ---------------- GEMM1: hidden = gelu(X[gather] @ W1[e] + b1) in bf16x3 MFMA ----------
// 128x128 tile, 4 waves (2x2), BK=32, global_load_lds staging, 16x16x32 bf16 MFMA
__global__ __launch_bounds__(256) void k_gemm1(
    const u16* __restrict__ xhi, const u16* __restrict__ xlo,
    const u16* __restrict__ w1h, const u16* __restrict__ w1l,
    const float* __restrict__ b1,
    const int* __restrict__ stok, const int* __restrict__ offs, const int* __restrict__ tilee,
    const u16* __restrict__ zbf,
    u16* __restrict__ hidh, u16* __restrict__ hidl, int chunk_base)
{
    __shared__ u16 smem[4 * 4096];  // 32KB: Ahi|Alo|Bhi|Blo, each [128 rows][32 k] bf16
    const int tid = threadIdx.x;
    const int mt  = chunk_base / 128 + blockIdx.x;
    if (mt * 128 >= offs[NEXP]) return;
    const int e  = tilee[mt];
    const int n0 = blockIdx.y * 128;
    const int w = tid >> 6, lane = tid & 63;
    const int wm = w >> 1, wn = w & 1;

    // staging: thread covers 16B chunk ci=tid (rows 0..63) and ci=256+tid (rows 64..127)
    const int srow = tid >> 2;
    const int skc  = (tid & 3) * 8;          // element offset within 32-elem row
    const int tA0 = stok[mt * 128 + srow];
    const int tA1 = stok[mt * 128 + 64 + srow];
    const u16* sA0h = (tA0 >= 0 ? xhi + (size_t)tA0 * DDIM : zbf) + skc;
    const u16* sA0l = (tA0 >= 0 ? xlo + (size_t)tA0 * DDIM : zbf) + skc;
    const u16* sA1h = (tA1 >= 0 ? xhi + (size_t)tA1 * DDIM : zbf) + skc;
    const u16* sA1l = (tA1 >= 0 ? xlo + (size_t)tA1 * DDIM : zbf) + skc;
    const u16* sB0h = w1h + ((size_t)e * HDIM + n0 + srow) * DDIM + skc;
    const u16* sB0l = w1l + ((size_t)e * HDIM + n0 + srow) * DDIM + skc;
    const u16* sB1h = w1h + ((size_t)e * HDIM + n0 + 64 + srow) * DDIM + skc;
    const u16* sB1l = w1l + ((size_t)e * HDIM + n0 + 64 + srow) * DDIM + skc;

    f32x4 acc[4][4] = {};

    for (int kt = 0; kt < DDIM; kt += 32) {
        gload16(sA0h + kt, &smem[0]     + w * 512);
        gload16(sA1h + kt, &smem[0]     + 2048 + w * 512);
        gload16(sA0l + kt, &smem[4096]  + w * 512);
        gload16(sA1l + kt, &smem[4096]  + 2048 + w * 512);
        gload16(sB0h + kt, &smem[8192]  + w * 512);
        gload16(sB1h + kt, &smem[8192]  + 2048 + w * 512);
        gload16(sB0l + kt, &smem[12288] + w * 512);
        gload16(sB1l + kt, &smem[12288] + 2048 + w * 512);
        __syncthreads();                       // drains vmcnt: LDS tiles ready
        const int fr = lane & 15, ko = (lane >> 4) * 8;
        short8 ah[4], al[4], bh[4], bl[4];
#pragma unroll
        for (int i = 0; i < 4; ++i) {
            ah[i] = *(const short8*)&smem[(wm * 64 + i * 16 + fr) * 32 + ko];
            al[i] = *(const short8*)&smem[4096 + (wm * 64 + i * 16 + fr) * 32 + ko];
            bh[i] = *(const short8*)&smem[8192 + (wn * 64 + i * 16 + fr) * 32 + ko];
            bl[i] = *(const short8*)&smem[12288 + (wn * 64 + i * 16 + fr) * 32 + ko];
        }
#pragma unroll
        for (int i = 0; i < 4; ++i)
#pragma unroll
            for (int j = 0; j < 4; ++j) {
                acc[i][j] = __builtin_amdgcn_mfma_f32_16x16x32_bf16(ah[i], bh[j], acc[i][j], 0, 0, 0);
                acc[i][j] = __builtin_amdgcn_mfma_f32_16x16x32_bf16(ah[i], bl[j], acc[i][j], 0, 0, 0);
                acc[i][j] = __builtin_amdgcn_mfma_f32_16x16x32_bf16(al[i], bh[j], acc[i][j], 0, 0, 0);
            }
        __syncthreads();                       // protect LDS before next overwrite
    }

    // epilogue: C/D layout col=lane&15, row=(lane>>4)*4+r (m89-verified)
    const int fr = lane & 15, fq = lane >> 4;
    const int lm0 = blockIdx.x * 128;
#pragma unroll
    for (int j = 0; j < 4; ++j) {
        const int col = n0 + wn * 64 + j * 16 + fr;
        const float bv = b1[(size_t)e * HDIM + col];
#pragma unroll
        for (int i = 0; i < 4; ++i) {
            const int rbase = wm * 64 + i * 16 + fq * 4;
#pragma unroll
            for (int r = 0; r < 4; ++r) {
                float v = gelu_f(acc[i][j][r] + bv);
                u16 h = f2bf(v);
                size_t o = (size_t)(lm0 + rbase + r) * HDIM + col;
                hidh[o] = h;
                hidl[o] = f2bf(v - bf2f(h));
            }
        }
    }
}

// ---------------- GEMM2: oslot = hidden @ W2[e] + b2 in bf16x3 MFMA -------------------
__global__ __launch_bounds__(256) void k_gemm2(
    const u16* __restrict__ hidh, const u16* __restrict__ hidl,
    const u16* __restrict__ w2h, const u16* __restrict__ w2l,
    const float* __restrict__ b2,
    const int* __restrict__ offs, const int* __restrict__ tilee,
    float* __restrict__ oslot, int chunk_base)
{
    __shared__ u16 smem[4 * 4096];
    const int tid = threadIdx.x;
    const int mt  = chunk_base / 128 + blockIdx.x;
    if (mt * 128 >= offs[NEXP]) return;
    const int e  = tilee[mt];
    const int n0 = blockIdx.y * 128;
    const int w = tid >> 6, lane = tid & 63;
    const int wm = w >> 1, wn = w & 1;

    const int srow = tid >> 2;
    const int skc  = (tid & 3) * 8;
    const int lm0  = blockIdx.x * 128;        // chunk-local row base
    const u16* sA0h = hidh + (size_t)(lm0 + srow) * HDIM + skc;
    const u16* sA0l = hidl + (size_t)(lm0 + srow) * HDIM + skc;
    const u16* sA1h = hidh + (size_t)(lm0 + 64 + srow) * HDIM + skc;
    const u16* sA1l = hidl + (size_t)(lm0 + 64 + srow) * HDIM + skc;
    const u16* sB0h = w2h + ((size_t)e * DDIM + n0 + srow) * HDIM + skc;
    const u16* sB0l = w2l + ((size_t)e * DDIM + n0 + srow) * HDIM + skc;
    const u16* sB1h = w2h + ((size_t)e * DDIM + n0 + 64 + srow) * HDIM + skc;
    const u16* sB1l = w2l + ((size_t)e * DDIM + n0 + 64 + srow) * HDIM + skc;

    f32x4 acc[4][4] = {};

    for (int kt = 0; kt < HDIM; kt += 32) {
        gload16(sA0h + kt, &smem[0]     + w * 512);
        gload16(sA1h + kt, &smem[0]     + 2048 + w * 512);
        gload16(sA0l + kt, &smem[4096]  + w * 512);
        gload16(sA1l + kt, &smem[4096]  + 2048 + w * 512);
        gload16(sB0h + kt, &smem[8192]  + w * 512);
        gload16(sB1h + kt, &smem[8192]  + 2048 + w * 512);
        gload16(sB0l + kt, &smem[12288] + w * 512);
        gload16(sB1l + kt, &smem[12288] + 2048 + w * 512);
        __syncthreads();
        const int fr = lane & 15, ko = (lane >> 4) * 8;
        short8 ah[4], al[4], bh[4], bl[4];
#pragma unroll
        for (int i = 0; i < 4; ++i) {
            ah[i] = *(const short8*)&smem[(wm * 64 + i * 16 + fr) * 32 + ko];
            al[i] = *(const short8*)&smem[4096 + (wm * 64 + i * 16 + fr) * 32 + ko];
            bh[i] = *(const short8*)&smem[8192 + (wn * 64 + i * 16 + fr) * 32 + ko];
            bl[i] = *(const short8*)&smem[12288 + (wn * 64 + i * 16 + fr) * 32 + ko];
        }
#pragma unroll
        for (int i = 0; i < 4; ++i)
#pragma unroll
            for (int j = 0; j < 4; ++j) {
                acc[i][j] = __builtin_amdgcn_mfma_f32_16x16x32_bf16(ah[i], bh[j], acc[i][j], 0, 0, 0);
                acc[i][j] = __builtin_amdgcn_mfma_f32_16x16x32_bf16(ah[i], bl[j], acc[i][j], 0, 0, 0);
                acc[i][j] = __builtin_amdgcn_mfma_f32_16x16x32_bf16(al[i], bh[j], acc[i][j], 0, 0, 0);
            }
        __syncthreads();
    }

    const int fr = lane & 15, fq = lane >> 4;
#pragma unroll
    for (int j = 0; j < 4; ++j) {
        const int col = n0 + wn * 64 + j * 16 + fr;
        const float bv = b2[(size_t)e * DDIM + col];
#pragma unroll
        for (int i = 0; i < 4; ++i) {
            const int rbase = wm * 64 + i * 16 + fq * 4;
#pragma unroll
            for (int r = 0; r < 4; ++r)
                oslot[(size_t)(mt * 128 + rbase + r) * DDIM + col] = acc[i][j][r] + bv;
        }
    }
}

// ---------------- combine: out[t] = w0*oslot[p0] + w1*oslot[p1] ----------------
__global__ void k_combine(const float* __restrict__ oslot, const int* __restrict__ spos,
                          const float* __restrict__ rw, float* __restrict__ out) {
    int i  = blockIdx.x * 256 + threadIdx.x;   // over T*D/4
    int t  = i >> 8;                            // D/4 = 256 float4 per token
    int d4 = (i & 255) * 4;
    float w0 = rw[t * 2], w1 = rw[t * 2 + 1];
    int   p0 = spos[t * 2], p1 = spos[t * 2 + 1];
    const float4 a = *(const float4*)(oslot + (size_t)p0 * DDIM + d4);
    const float4 b = *(const float4*)(oslot + (size_t)p1 * DDIM + d4);
    float4 o;
    o.x = w0 * a.x + w1 * b.x; o.y = w0 * a.y + w1 * b.y;
    o.z = w0 * a.z + w1 * b.z; o.w = w0 * a.w + w1 * b.w;
    *(float4*)(out + (size_t)t * DDIM + d4) = o;
}

extern "C" void kernel_launch(void* const* d_in, const int* in_sizes, int n_in,
                              void* d_out, int out_size, void* d_ws, size_t ws_size,
                              hipStream_t stream) {
    const float* x  = (const float*)d_in[0];
    const float* Wr = (const float*)d_in[1];
    const float* W1 = (const float*)d_in[2];
    const float* b1 = (const float*)d_in[3];
    const float* W2 = (const float*)d_in[4];
    const float* b2 = (const float*)d_in[5];
    float* out = (float*)d_out;

    char* ws = (char*)d_ws;
    int*   ridx  = (int*)(ws + OFF_RIDX);
    float* rw    = (float*)(ws + OFF_RW);
    int*   spos  = (int*)(ws + OFF_SPOS);
    int*   offs  = (int*)(ws + OFF_OFFS);
    int*   curs  = (int*)(ws + OFF_CURS);
    int*   tilee = (int*)(ws + OFF_TILEE);
    int*   stok  = (int*)(ws + OFF_STOK);
    float* swt   = (float*)(ws + OFF_SWT);
    u16*   zbf   = (u16*)(ws + OFF_ZBF);
    u16*   xhi   = (u16*)(ws + OFF_XHI);
    u16*   xlo   = (u16*)(ws + OFF_XLO);
    u16*   w1h   = (u16*)(ws + OFF_W1H);
    u16*   w1l   = (u16*)(ws + OFF_W1L);
    u16*   w2h   = (u16*)(ws + OFF_W2H);
    u16*   w2l   = (u16*)(ws + OFF_W2L);
    u16*   hidh  = (u16*)(ws + OFF_HIDH);
    u16*   hidl  = (u16*)(ws + OFF_HIDL);
    float* oslot = (float*)(ws + OFF_OSLOT);

    k_router <<<T_TOK / 4, 256, 0, stream>>>(x, Wr, ridx, rw);
    k_offsets<<<1, 256, 0, stream>>>(ridx, offs, curs, tilee, stok, swt, zbf);
    k_scatter<<<T_TOK / 256, 256, 0, stream>>>(ridx, rw, curs, stok, swt, spos);
    k_split_x<<<2048, 256, 0, stream>>>(x, xhi, xlo);
    k_split_w<<<dim3(DDIM / 32, HDIM / 32, NEXP), 256, 0, stream>>>(W1, w1h, w1l, DDIM, HDIM);
    k_split_w<<<dim3(HDIM / 32, DDIM / 32, NEXP), 256, 0, stream>>>(W2, w2h, w2l, HDIM, DDIM);

    for (int c = 0; c < NCHUNK; ++c) {
        k_gemm1<<<dim3(CHUNK / 128, HDIM / 128), 256, 0, stream>>>(
            xhi, xlo, w1h, w1l, b1, stok, offs, tilee, zbf, hidh, hidl, c * CHUNK);
        k_gemm2<<<dim3(CHUNK / 128, DDIM / 128), 256, 0, stream>>>(
            hidh, hidl, w2h, w2l, b2, offs, tilee, oslot, c * CHUNK);
    }
    k_combine<<<T_TOK * DDIM / 4 / 256, 256, 0, stream>>>(oslot, spos, rw, out);
}

// Round 3
// 1945.890 us; speedup vs baseline: 1.0063x; 1.0063x over previous
//
#include <hip/hip_runtime.h>

// ---- problem constants (fixed by reference) ----
#define T_TOK 8192      // B*S tokens
#define DDIM  1024
#define HDIM  4096
#define NEXP  8
#define TOPK  2

#define NSLOT_CAP 20480          // 16384 + 8*127 pad, rounded up
#define NTILE     (NSLOT_CAP / 128)
#define CHUNK     4096           // slots per hidden chunk (fallback mode)
#define NCHUNK    5

typedef __attribute__((ext_vector_type(8))) short short8;  // 8 bf16 = 4 VGPRs
typedef __attribute__((ext_vector_type(4))) float f32x4;
typedef unsigned short u16;

// ---- workspace layout (bytes) ----
// common small region
#define OFF_RIDX  0x0ul          // [T][2] int
#define OFF_RW    0x10000ul      // [T][2] float
#define OFF_SPOS  0x20000ul      // [T][2] int (slot position per (t,k))
#define OFF_OFFS  0x30000ul      // [9] int
#define OFF_CURS  0x30100ul      // [8] int
#define OFF_TILEE 0x30200ul      // [NTILE] int
#define OFF_STOK  0x31000ul      // [NSLOT_CAP] int
#define OFF_SWT   0x45000ul      // [NSLOT_CAP] float
#define OFF_ZBF   0x59000ul      // 2048 bf16 zeros (pad-row source)
#define OFF_XHI   0x100000ul     // [T][D] bf16 hi (16MB)
#define OFF_XLO   0x1100000ul    // [T][D] bf16 lo (16MB)
#define OFF_W1H   0x2100000ul    // [E][H][D] bf16 hi, transposed (64MB)
#define OFF_W1L   0x6100000ul    // (64MB)
#define OFF_W2H   0xA100000ul    // [E][D][H] bf16 hi, transposed (64MB)
#define OFF_W2L   0xE100000ul    // (64MB)
// chunked (fallback) tail: hidden chunk + full oslot
#define OFF_HIDH_C 0x12100000ul  // [CHUNK][H] bf16 hi (32MB)
#define OFF_HIDL_C 0x14100000ul  // (32MB)
#define OFF_OSLOT_C 0x16100000ul // [NSLOT_CAP][D] fp32 (80MB) -> end 453MB
// full-mode tail: full hidden; oslot aliases W1 region (gemm1 done before gemm2)
#define OFF_HIDH_F 0x12100000ul  // [NSLOT_CAP][H] bf16 hi (160MB)
#define OFF_HIDL_F 0x1C100000ul  // (160MB)
#define OFF_OSLOT_F OFF_W1H      // 80MB fits in 128MB W1 region
#define FULL_NEED  0x26100000ul  // ~638MB

__device__ __forceinline__ u16 f2bf(float f) {          // RNE fp32->bf16
    unsigned u = __float_as_uint(f);
    u += 0x7fffu + ((u >> 16) & 1u);
    return (u16)(u >> 16);
}
__device__ __forceinline__ float bf2f(u16 h) {
    return __uint_as_float(((unsigned)h) << 16);
}
__device__ __forceinline__ float gelu_f(float v) {
    // jax.nn.gelu approximate=True
    float u  = 0.7978845608028654f * v * (1.0f + 0.044715f * v * v);
    float ex = __expf(2.0f * u);
    float th = 1.0f - 2.0f / (ex + 1.0f);
    return 0.5f * v * (1.0f + th);
}
__device__ __forceinline__ void gload16(const void* g, void* l) {
    // async global->LDS, 16B/lane; LDS dest = wave-uniform base + lane*16
    __builtin_amdgcn_global_load_lds((const __attribute__((address_space(1))) unsigned*)g,
                                     (__attribute__((address_space(3))) unsigned*)l, 16, 0, 0);
}

// ---------------- router: one wave per token (fp32 exact) ----------------
__global__ void k_router(const float* __restrict__ x, const float* __restrict__ Wr,
                         int* __restrict__ ridx, float* __restrict__ rw) {
    int gt   = (blockIdx.x * blockDim.x + threadIdx.x) >> 6;
    int lane = threadIdx.x & 63;
    if (gt >= T_TOK) return;
    const float* xr = x + (size_t)gt * DDIM;
    float acc[NEXP];
#pragma unroll
    for (int e = 0; e < NEXP; ++e) acc[e] = 0.f;
#pragma unroll
    for (int j = 0; j < DDIM / 64; ++j) {
        float xv = xr[j * 64 + lane];
        const float4 w0 = *(const float4*)(Wr + (size_t)(j * 64 + lane) * NEXP);
        const float4 w1 = *(const float4*)(Wr + (size_t)(j * 64 + lane) * NEXP + 4);
        acc[0] += xv * w0.x; acc[1] += xv * w0.y; acc[2] += xv * w0.z; acc[3] += xv * w0.w;
        acc[4] += xv * w1.x; acc[5] += xv * w1.y; acc[6] += xv * w1.z; acc[7] += xv * w1.w;
    }
#pragma unroll
    for (int off = 32; off > 0; off >>= 1) {
#pragma unroll
        for (int e = 0; e < NEXP; ++e) acc[e] += __shfl_xor(acc[e], off, 64);
    }
    if (lane == 0) {
        float mx = acc[0];
#pragma unroll
        for (int e = 1; e < NEXP; ++e) mx = fmaxf(mx, acc[e]);
        float p[NEXP]; float s = 0.f;
#pragma unroll
        for (int e = 0; e < NEXP; ++e) { p[e] = __expf(acc[e] - mx); s += p[e]; }
        float inv = 1.f / s;
        int i0 = 0;
#pragma unroll
        for (int e = 1; e < NEXP; ++e) if (acc[e] > acc[i0]) i0 = e;   // ties -> lowest idx
        int i1 = (i0 == 0) ? 1 : 0;
#pragma unroll
        for (int e = 0; e < NEXP; ++e) if (e != i0 && acc[e] > acc[i1]) i1 = e;
        float w0 = 0.f, w1 = 0.f;
#pragma unroll
        for (int e = 0; e < NEXP; ++e) { if (e == i0) w0 = p[e]; if (e == i1) w1 = p[e]; }
        ridx[gt * 2 + 0] = i0; ridx[gt * 2 + 1] = i1;
        rw  [gt * 2 + 0] = w0 * inv; rw[gt * 2 + 1] = w1 * inv;
    }
}

// ---------------- counts -> padded offsets -> pad slots (+ zero zbf) ----------------
__global__ void k_offsets(const int* __restrict__ ridx, int* __restrict__ offs,
                          int* __restrict__ curs, int* __restrict__ tilee,
                          int* __restrict__ stok, float* __restrict__ swt,
                          u16* __restrict__ zbf) {
    __shared__ int scnt[NEXP];
    __shared__ int soff[NEXP + 1];
    int tid = threadIdx.x;
    for (int i = tid; i < 2048; i += 256) zbf[i] = 0;   // ws is poisoned each call
    if (tid < NEXP) scnt[tid] = 0;
    __syncthreads();
    int c[NEXP];
#pragma unroll
    for (int q = 0; q < NEXP; ++q) c[q] = 0;
    for (int i = tid; i < T_TOK * TOPK; i += 256) {
        int e = ridx[i];
#pragma unroll
        for (int q = 0; q < NEXP; ++q) c[q] += (e == q) ? 1 : 0;
    }
#pragma unroll
    for (int off = 32; off > 0; off >>= 1) {
#pragma unroll
        for (int q = 0; q < NEXP; ++q) c[q] += __shfl_xor(c[q], off, 64);
    }
    if ((tid & 63) == 0) {
#pragma unroll
        for (int q = 0; q < NEXP; ++q) atomicAdd(&scnt[q], c[q]);
    }
    __syncthreads();
    if (tid == 0) {
        int o = 0;
        for (int q = 0; q < NEXP; ++q) {
            soff[q] = o;
            o += (scnt[q] + 127) & ~127;
        }
        soff[NEXP] = o;
        for (int q = 0; q <= NEXP; ++q) offs[q] = soff[q];
        for (int q = 0; q < NEXP; ++q) curs[q] = soff[q];
        for (int tt = 0; tt < NTILE; ++tt) {
            int e = -1;
            for (int q = 0; q < NEXP; ++q)
                if (tt * 128 >= soff[q] && tt * 128 < soff[q + 1]) e = q;
            tilee[tt] = e;
        }
    }
    __syncthreads();
    int total = soff[NEXP];
    for (int sIdx = tid; sIdx < NSLOT_CAP; sIdx += 256) {
        bool pad = (sIdx >= total);
        if (!pad) {
            int e = 0;
#pragma unroll
            for (int q = 1; q < NEXP; ++q) if (sIdx >= soff[q]) e = q;
            if (sIdx >= soff[e] + scnt[e]) pad = true;
        }
        if (pad) { stok[sIdx] = -1; swt[sIdx] = 0.f; }
    }
}

// ---------------- scatter tokens into slots (wave-aggregated atomics) ----------------
__global__ void k_scatter(const int* __restrict__ ridx, const float* __restrict__ rw,
                          int* __restrict__ curs, int* __restrict__ stok,
                          float* __restrict__ swt, int* __restrict__ spos) {
    int t    = blockIdx.x * 256 + threadIdx.x;
    int lane = threadIdx.x & 63;
#pragma unroll
    for (int k = 0; k < TOPK; ++k) {
        int e   = ridx[t * 2 + k];
        float w = rw[t * 2 + k];
#pragma unroll
        for (int q = 0; q < NEXP; ++q) {
            unsigned long long m = __ballot(e == q);
            if (e == q) {
                int rank   = __popcll(m & ((1ull << lane) - 1ull));
                int leader = __ffsll((unsigned long long)m) - 1;
                int base = 0;
                if (lane == leader) base = atomicAdd(&curs[q], __popcll(m));
                base = __shfl(base, leader, 64);
                int pos = base + rank;
                stok[pos] = t;
                swt[pos]  = w;
                spos[t * 2 + k] = pos;
            }
        }
    }
}

// ---------------- fp32 -> (hi,lo) bf16, elementwise (for x) ----------------
__global__ void k_split_x(const float* __restrict__ x, u16* __restrict__ hi,
                          u16* __restrict__ lo) {
    for (int i = blockIdx.x * 256 + threadIdx.x; i < T_TOK * DDIM / 4; i += gridDim.x * 256) {
        float4 v = ((const float4*)x)[i];
        u16 h0 = f2bf(v.x), h1 = f2bf(v.y), h2 = f2bf(v.z), h3 = f2bf(v.w);
        ushort4 hv; hv.x = h0; hv.y = h1; hv.z = h2; hv.w = h3;
        ushort4 lv;
        lv.x = f2bf(v.x - bf2f(h0)); lv.y = f2bf(v.y - bf2f(h1));
        lv.z = f2bf(v.z - bf2f(h2)); lv.w = f2bf(v.w - bf2f(h3));
        ((ushort4*)hi)[i] = hv;
        ((ushort4*)lo)[i] = lv;
    }
}

// ---------------- fp32 [E][R][C] -> transposed (hi,lo) bf16 [E][C][R] ----------------
__global__ __launch_bounds__(256) void k_split_w(const float* __restrict__ Wsrc,
        u16* __restrict__ hi, u16* __restrict__ lo, int R, int C) {
    __shared__ float t[32][33];
    const int e  = blockIdx.z;
    const int r0 = blockIdx.x * 32, c0 = blockIdx.y * 32;
    const float* src = Wsrc + (size_t)e * R * C;
    const int rr = threadIdx.x >> 3, cc = (threadIdx.x & 7) * 4;
    float4 v = *(const float4*)(src + (size_t)(r0 + rr) * C + c0 + cc);
    t[rr][cc] = v.x; t[rr][cc + 1] = v.y; t[rr][cc + 2] = v.z; t[rr][cc + 3] = v.w;
    __syncthreads();
    const int orow = threadIdx.x >> 3, oc = (threadIdx.x & 7) * 4;
    ushort4 hv, lv;
    float f0 = t[oc + 0][orow], f1 = t[oc + 1][orow], f2 = t[oc + 2][orow], f3 = t[oc + 3][orow];
    hv.x = f2bf(f0); hv.y = f2bf(f1); hv.z = f2bf(f2); hv.w = f2bf(f3);
    lv.x = f2bf(f0 - bf2f(hv.x)); lv.y = f2bf(f1 - bf2f(hv.y));
    lv.z = f2bf(f2 - bf2f(hv.z)); lv.w = f2bf(f3 - bf2f(hv.w));
    size_t ob = ((size_t)e * C + c0 + orow) * R + r0 + oc;
    *(ushort4*)(hi + ob) = hv;
    *(ushort4*)(lo + ob) = lv;
}

// ---------------- GEMM1: hidden = gelu(X[gather] @ W1[e] + b1) in bf16x3 MFMA ----------
// 128x128 tile, 4 waves (2x2), BK=32, global_load_lds staging, 16x16x32 bf16 MFMA
__global__ __launch_bounds__(256) void k_gemm1(
    const u16* __restrict__ xhi, const u16* __restrict__ xlo,
    const u16* __restrict__ w1h, const u16* __restrict__ w1l,
    const float* __restrict__ b1,
    const int* __restrict__ stok, const int* __restrict__ offs, const int* __restrict__ tilee,
    const u16* __restrict__ zbf,
    u16* __restrict__ hidh, u16* __restrict__ hidl, int chunk_base)
{
    __shared__ u16 smem[4 * 4096];  // 32KB: Ahi|Alo|Bhi|Blo, each [128 rows][32 k] bf16
    const int tid = threadIdx.x;
    const int mt  = chunk_base / 128 + blockIdx.x;
    if (mt * 128 >= offs[NEXP]) return;
    const int e  = tilee[mt];
    const int n0 = blockIdx.y * 128;
    const int w = tid >> 6, lane = tid & 63;
    const int wm = w >> 1, wn = w & 1;

    // staging: thread covers 16B chunk ci=tid (rows 0..63) and ci=256+tid (rows 64..127)
    const int srow = tid >> 2;
    const int skc  = (tid & 3) * 8;          // element offset within 32-elem row
    const int tA0 = stok[mt * 128 + srow];
    const int tA1 = stok[mt * 128 + 64 + srow];
    const u16* sA0h = (tA0 >= 0 ? xhi + (size_t)tA0 * DDIM : zbf) + skc;
    const u16* sA0l = (tA0 >= 0 ? xlo + (size_t)tA0 * DDIM : zbf) + skc;
    const u16* sA1h = (tA1 >= 0 ? xhi + (size_t)tA1 * DDIM : zbf) + skc;
    const u16* sA1l = (tA1 >= 0 ? xlo + (size_t)tA1 * DDIM : zbf) + skc;
    const u16* sB0h = w1h + ((size_t)e * HDIM + n0 + srow) * DDIM + skc;
    const u16* sB0l = w1l + ((size_t)e * HDIM + n0 + srow) * DDIM + skc;
    const u16* sB1h = w1h + ((size_t)e * HDIM + n0 + 64 + srow) * DDIM + skc;
    const u16* sB1l = w1l + ((size_t)e * HDIM + n0 + 64 + srow) * DDIM + skc;

    f32x4 acc[4][4] = {};

    for (int kt = 0; kt < DDIM; kt += 32) {
        gload16(sA0h + kt, &smem[0]     + w * 512);
        gload16(sA1h + kt, &smem[0]     + 2048 + w * 512);
        gload16(sA0l + kt, &smem[4096]  + w * 512);
        gload16(sA1l + kt, &smem[4096]  + 2048 + w * 512);
        gload16(sB0h + kt, &smem[8192]  + w * 512);
        gload16(sB1h + kt, &smem[8192]  + 2048 + w * 512);
        gload16(sB0l + kt, &smem[12288] + w * 512);
        gload16(sB1l + kt, &smem[12288] + 2048 + w * 512);
        __syncthreads();                       // drains vmcnt: LDS tiles ready
        const int fr = lane & 15, ko = (lane >> 4) * 8;
        short8 ah[4], al[4], bh[4], bl[4];
#pragma unroll
        for (int i = 0; i < 4; ++i) {
            ah[i] = *(const short8*)&smem[(wm * 64 + i * 16 + fr) * 32 + ko];
            al[i] = *(const short8*)&smem[4096 + (wm * 64 + i * 16 + fr) * 32 + ko];
            bh[i] = *(const short8*)&smem[8192 + (wn * 64 + i * 16 + fr) * 32 + ko];
            bl[i] = *(const short8*)&smem[12288 + (wn * 64 + i * 16 + fr) * 32 + ko];
        }
#pragma unroll
        for (int i = 0; i < 4; ++i)
#pragma unroll
            for (int j = 0; j < 4; ++j) {
                acc[i][j] = __builtin_amdgcn_mfma_f32_16x16x32_bf16(ah[i], bh[j], acc[i][j], 0, 0, 0);
                acc[i][j] = __builtin_amdgcn_mfma_f32_16x16x32_bf16(ah[i], bl[j], acc[i][j], 0, 0, 0);
                acc[i][j] = __builtin_amdgcn_mfma_f32_16x16x32_bf16(al[i], bh[j], acc[i][j], 0, 0, 0);
            }
        __syncthreads();                       // protect LDS before next overwrite
    }

    // epilogue: C/D layout col=lane&15, row=(lane>>4)*4+r (m89-verified)
    const int fr = lane & 15, fq = lane >> 4;
    const int lm0 = mt * 128 - chunk_base;     // hidden-buffer row base
#pragma unroll
    for (int j = 0; j < 4; ++j) {
        const int col = n0 + wn * 64 + j * 16 + fr;
        const float bv = b1[(size_t)e * HDIM + col];
#pragma unroll
        for (int i = 0; i < 4; ++i) {
            const int rbase = wm * 64 + i * 16 + fq * 4;
#pragma unroll
            for (int r = 0; r < 4; ++r) {
                float v = gelu_f(acc[i][j][r] + bv);
                u16 h = f2bf(v);
                size_t o = (size_t)(lm0 + rbase + r) * HDIM + col;
                hidh[o] = h;
                hidl[o] = f2bf(v - bf2f(h));
            }
        }
    }
}

// ---------------- GEMM2: oslot = hidden @ W2[e] + b2 in bf16x3 MFMA -------------------
__global__ __launch_bounds__(256) void k_gemm2(
    const u16* __restrict__ hidh, const u16* __restrict__ hidl,
    const u16* __restrict__ w2h, const u16* __restrict__ w2l,
    const float* __restrict__ b2,
    const int* __restrict__ offs, const int* __restrict__ tilee,
    float* __restrict__ oslot, int chunk_base)
{
    __shared__ u16 smem[4 * 4096];
    const int tid = threadIdx.x;
    const int mt  = chunk_base / 128 + blockIdx.x;
    if (mt * 128 >= offs[NEXP]) return;
    const int e  = tilee[mt];
    const int n0 = blockIdx.y * 128;
    const int w = tid >> 6, lane = tid & 63;
    const int wm = w >> 1, wn = w & 1;

    const int srow = tid >> 2;
    const int skc  = (tid & 3) * 8;
    const int lm0  = mt * 128 - chunk_base;   // hidden-buffer row base
    const u16* sA0h = hidh + (size_t)(lm0 + srow) * HDIM + skc;
    const u16* sA0l = hidl + (size_t)(lm0 + srow) * HDIM + skc;
    const u16* sA1h = hidh + (size_t)(lm0 + 64 + srow) * HDIM + skc;
    const u16* sA1l = hidl + (size_t)(lm0 + 64 + srow) * HDIM + skc;
    const u16* sB0h = w2h + ((size_t)e * DDIM + n0 + srow) * HDIM + skc;
    const u16* sB0l = w2l + ((size_t)e * DDIM + n0 + srow) * HDIM + skc;
    const u16* sB1h = w2h + ((size_t)e * DDIM + n0 + 64 + srow) * HDIM + skc;
    const u16* sB1l = w2l + ((size_t)e * DDIM + n0 + 64 + srow) * HDIM + skc;

    f32x4 acc[4][4] = {};

    for (int kt = 0; kt < HDIM; kt += 32) {
        gload16(sA0h + kt, &smem[0]     + w * 512);
        gload16(sA1h + kt, &smem[0]     + 2048 + w * 512);
        gload16(sA0l + kt, &smem[4096]  + w * 512);
        gload16(sA1l + kt, &smem[4096]  + 2048 + w * 512);
        gload16(sB0h + kt, &smem[8192]  + w * 512);
        gload16(sB1h + kt, &smem[8192]  + 2048 + w * 512);
        gload16(sB0l + kt, &smem[12288] + w * 512);
        gload16(sB1l + kt, &smem[12288] + 2048 + w * 512);
        __syncthreads();
        const int fr = lane & 15, ko = (lane >> 4) * 8;
        short8 ah[4], al[4], bh[4], bl[4];
#pragma unroll
        for (int i = 0; i < 4; ++i) {
            ah[i] = *(const short8*)&smem[(wm * 64 + i * 16 + fr) * 32 + ko];
            al[i] = *(const short8*)&smem[4096 + (wm * 64 + i * 16 + fr) * 32 + ko];
            bh[i] = *(const short8*)&smem[8192 + (wn * 64 + i * 16 + fr) * 32 + ko];
            bl[i] = *(const short8*)&smem[12288 + (wn * 64 + i * 16 + fr) * 32 + ko];
        }
#pragma unroll
        for (int i = 0; i < 4; ++i)
#pragma unroll
            for (int j = 0; j < 4; ++j) {
                acc[i][j] = __builtin_amdgcn_mfma_f32_16x16x32_bf16(ah[i], bh[j], acc[i][j], 0, 0, 0);
                acc[i][j] = __builtin_amdgcn_mfma_f32_16x16x32_bf16(ah[i], bl[j], acc[i][j], 0, 0, 0);
                acc[i][j] = __builtin_amdgcn_mfma_f32_16x16x32_bf16(al[i], bh[j], acc[i][j], 0, 0, 0);
            }
        __syncthreads();
    }

    const int fr = lane & 15, fq = lane >> 4;
#pragma unroll
    for (int j = 0; j < 4; ++j) {
        const int col = n0 + wn * 64 + j * 16 + fr;
        const float bv = b2[(size_t)e * DDIM + col];
#pragma unroll
        for (int i = 0; i < 4; ++i) {
            const int rbase = wm * 64 + i * 16 + fq * 4;
#pragma unroll
            for (int r = 0; r < 4; ++r)
                oslot[(size_t)(mt * 128 + rbase + r) * DDIM + col] = acc[i][j][r] + bv;
        }
    }
}

// ---------------- combine: out[t] = w0*oslot[p0] + w1*oslot[p1] ----------------
__global__ void k_combine(const float* __restrict__ oslot, const int* __restrict__ spos,
                          const float* __restrict__ rw, float* __restrict__ out) {
    int i  = blockIdx.x * 256 + threadIdx.x;   // over T*D/4
    int t  = i >> 8;                            // D/4 = 256 float4 per token
    int d4 = (i & 255) * 4;
    float w0 = rw[t * 2], w1 = rw[t * 2 + 1];
    int   p0 = spos[t * 2], p1 = spos[t * 2 + 1];
    const float4 a = *(const float4*)(oslot + (size_t)p0 * DDIM + d4);
    const float4 b = *(const float4*)(oslot + (size_t)p1 * DDIM + d4);
    float4 o;
    o.x = w0 * a.x + w1 * b.x; o.y = w0 * a.y + w1 * b.y;
    o.z = w0 * a.z + w1 * b.z; o.w = w0 * a.w + w1 * b.w;
    *(float4*)(out + (size_t)t * DDIM + d4) = o;
}

extern "C" void kernel_launch(void* const* d_in, const int* in_sizes, int n_in,
                              void* d_out, int out_size, void* d_ws, size_t ws_size,
                              hipStream_t stream) {
    const float* x  = (const float*)d_in[0];
    const float* Wr = (const float*)d_in[1];
    const float* W1 = (const float*)d_in[2];
    const float* b1 = (const float*)d_in[3];
    const float* W2 = (const float*)d_in[4];
    const float* b2 = (const float*)d_in[5];
    float* out = (float*)d_out;

    char* ws = (char*)d_ws;
    int*   ridx  = (int*)(ws + OFF_RIDX);
    float* rw    = (float*)(ws + OFF_RW);
    int*   spos  = (int*)(ws + OFF_SPOS);
    int*   offs  = (int*)(ws + OFF_OFFS);
    int*   curs  = (int*)(ws + OFF_CURS);
    int*   tilee = (int*)(ws + OFF_TILEE);
    int*   stok  = (int*)(ws + OFF_STOK);
    float* swt   = (float*)(ws + OFF_SWT);
    u16*   zbf   = (u16*)(ws + OFF_ZBF);
    u16*   xhi   = (u16*)(ws + OFF_XHI);
    u16*   xlo   = (u16*)(ws + OFF_XLO);
    u16*   w1h   = (u16*)(ws + OFF_W1H);
    u16*   w1l   = (u16*)(ws + OFF_W1L);
    u16*   w2h   = (u16*)(ws + OFF_W2H);
    u16*   w2l   = (u16*)(ws + OFF_W2L);

    k_router <<<T_TOK / 4, 256, 0, stream>>>(x, Wr, ridx, rw);
    k_offsets<<<1, 256, 0, stream>>>(ridx, offs, curs, tilee, stok, swt, zbf);
    k_scatter<<<T_TOK / 256, 256, 0, stream>>>(ridx, rw, curs, stok, swt, spos);
    k_split_x<<<2048, 256, 0, stream>>>(x, xhi, xlo);
    k_split_w<<<dim3(DDIM / 32, HDIM / 32, NEXP), 256, 0, stream>>>(W1, w1h, w1l, DDIM, HDIM);
    k_split_w<<<dim3(HDIM / 32, DDIM / 32, NEXP), 256, 0, stream>>>(W2, w2h, w2l, HDIM, DDIM);

    if (ws_size >= FULL_NEED) {
        // full mode: one gemm1 launch over all slot tiles, then one gemm2 launch.
        // oslot aliases the W1 split region (gemm1 fully precedes gemm2 in-stream).
        u16*   hidh  = (u16*)(ws + OFF_HIDH_F);
        u16*   hidl  = (u16*)(ws + OFF_HIDL_F);
        float* oslot = (float*)(ws + OFF_OSLOT_F);
        k_gemm1<<<dim3(NTILE, HDIM / 128), 256, 0, stream>>>(
            xhi, xlo, w1h, w1l, b1, stok, offs, tilee, zbf, hidh, hidl, 0);
        k_gemm2<<<dim3(NTILE, DDIM / 128), 256, 0, stream>>>(
            hidh, hidl, w2h, w2l, b2, offs, tilee, oslot, 0);
        k_combine<<<T_TOK * DDIM / 4 / 256, 256, 0, stream>>>(oslot, spos, rw, out);
    } else {
        // fallback: chunked hidden buffer (known-good round-2 path)
        u16*   hidh  = (u16*)(ws + OFF_HIDH_C);
        u16*   hidl  = (u16*)(ws + OFF_HIDL_C);
        float* oslot = (float*)(ws + OFF_OSLOT_C);
        for (int c = 0; c < NCHUNK; ++c) {
            k_gemm1<<<dim3(CHUNK / 128, HDIM / 128), 256, 0, stream>>>(
                xhi, xlo, w1h, w1l, b1, stok, offs, tilee, zbf, hidh, hidl, c * CHUNK);
            k_gemm2<<<dim3(CHUNK / 128, DDIM / 128), 256, 0, stream>>>(
                hidh, hidl, w2h, w2l, b2, offs, tilee, oslot, c * CHUNK);
        }
        k_combine<<<T_TOK * DDIM / 4 / 256, 256, 0, stream>>>(oslot, spos, rw, out);
    }
}